// Round 1
// baseline (292.185 us; speedup 1.0000x reference)
//
#include <hip/hip_runtime.h>
#include <stdint.h>

// DCT2D: y = Dh @ x @ Dw^T per (b,c); B=32,H=W=512,C=3, fp32 in/out.
// Strategy: bf16 MFMA (16x16x32), two GEMM passes via bf16 intermediate
// Y[b,k,c,w] in workspace. D (512x512) generated on device (Dh==Dw).

typedef __bf16 bf16_t;
typedef bf16_t bf16x8 __attribute__((ext_vector_type(8)));
typedef float  f32x4  __attribute__((ext_vector_type(4)));

__device__ __forceinline__ uint32_t f2bf(float f) {
    union { float f; uint32_t u; } v; v.f = f;
    uint32_t r = v.u + 0x7fffu + ((v.u >> 16) & 1u);   // RNE
    return r >> 16;
}

__device__ __forceinline__ f32x4 mfma16(bf16x8 a, bf16x8 b, f32x4 c) {
    return __builtin_amdgcn_mfma_f32_16x16x32_bf16(a, b, c, 0, 0, 0);
}

__device__ __forceinline__ void load_lds16(const void* g, void* l) {
    __builtin_amdgcn_global_load_lds(
        (const __attribute__((address_space(1))) uint32_t*)g,
        (__attribute__((address_space(3))) uint32_t*)l, 16, 0, 0);
}

// ---------------- D matrix generation (bf16, row-major D[k][h]) -------------
__global__ __launch_bounds__(256) void gen_dct(uint16_t* __restrict__ Dbf) {
    int idx = blockIdx.x * 256 + threadIdx.x;      // 512*512 elems
    int k = idx >> 9, h = idx & 511;
    int phase = ((2 * h + 1) * k) & 2047;          // exact mod-2048 reduction
    float ang = (float)phase * 3.0679615757712823e-3f;   // pi/1024
    float s = (k == 0) ? 0.04419417382415922f : 0.0625f; // sqrt(1/512), sqrt(2/512)
    Dbf[idx] = (uint16_t)f2bf(__cosf(ang) * s);
}

// ---------------- Pass 1: Y[b,k,c,w] = sum_h D[k,h] * x[b,h,w,c] ------------
// GEMM per b: C[m=k(128-tile), n=remapped (c,w) col (96-tile)], K=h, BK=32.
// A = D tile via global_load_lds -> LDS [m][h] rows of 64B.
// B = x tile fp32->bf16, transposed in-register into LDS [col][h], XOR-swizzled.
__global__ __launch_bounds__(256, 3) void pass1(const float* __restrict__ x,
                                                const uint16_t* __restrict__ Dbf,
                                                uint16_t* __restrict__ Y) {
    __shared__ __align__(16) uint16_t Alds[128 * 32];   // 8 KB
    __shared__ __align__(16) uint16_t Blds[96 * 32];    // 6 KB (swizzled)
    const int t = threadIdx.x;
    const int lane = t & 63, wv = t >> 6;
    const int nt = blockIdx.x;   // j-tile 0..15 (96 cols = 32 w * 3 c)
    const int mt = blockIdx.y;   // k-tile 0..3
    const int b  = blockIdx.z;
    const float* xb = x + (size_t)b * (512 * 1536);

    // B-staging mapping (threads 0..191): jl -> (w,c); col remap so that
    // MFMA col-tiles 2c/2c+1 hold even/odd w (enables paired bf16 stores).
    const int jl = t % 96;
    const int hh = t / 96;                       // 0/1 -> h-halves of 16
    const int wl = jl / 3, cc = jl - 3 * wl;
    const int ncol = cc * 32 + ((wl >> 1) + ((wl & 1) << 4));
    const int xv = (ncol >> 1) & 3;              // 16B-chunk XOR swizzle
    const int jg = nt * 96 + jl;

    f32x4 acc[2][6] = {};

    for (int kt = 0; kt < 16; ++kt) {
        __syncthreads();
        // A: D tile (128 rows x 64 B), 512 16B-chunks, lane-linear LDS
        {
            int q = t;
            load_lds16(Dbf + (size_t)(mt * 128 + (q >> 2)) * 512 + kt * 32 + (q & 3) * 8,
                       Alds + q * 8);
            int q2 = t + 256;
            load_lds16(Dbf + (size_t)(mt * 128 + (q2 >> 2)) * 512 + kt * 32 + (q2 & 3) * 8,
                       Alds + q2 * 8);
        }
        // B: x tile 32h x 96j fp32 -> bf16, transposed to [col][h]
        if (t < 192) {
            const float* src = xb + (size_t)(kt * 32 + hh * 16) * 1536 + jg;
            float v[16];
#pragma unroll
            for (int r = 0; r < 16; ++r) v[r] = src[(size_t)r * 1536];
            uint32_t p[8];
#pragma unroll
            for (int i = 0; i < 8; ++i)
                p[i] = f2bf(v[2 * i]) | (f2bf(v[2 * i + 1]) << 16);
            *(uint4*)&Blds[ncol * 32 + (((hh * 2 + 0) ^ xv) << 3)] =
                make_uint4(p[0], p[1], p[2], p[3]);
            *(uint4*)&Blds[ncol * 32 + (((hh * 2 + 1) ^ xv) << 3)] =
                make_uint4(p[4], p[5], p[6], p[7]);
        }
        __syncthreads();

        bf16x8 aq[2];
#pragma unroll
        for (int i = 0; i < 2; ++i)
            aq[i] = *(bf16x8*)&Alds[((wv * 2 + i) * 16 + (lane & 15)) * 32 + ((lane >> 4) << 3)];
#pragma unroll
        for (int tt = 0; tt < 6; ++tt) {
            int col = tt * 16 + (lane & 15);
            bf16x8 bq = *(bf16x8*)&Blds[col * 32 + (((lane >> 4) ^ ((col >> 1) & 3)) << 3)];
            acc[0][tt] = mfma16(aq[0], bq, acc[0][tt]);
            acc[1][tt] = mfma16(aq[1], bq, acc[1][tt]);
        }
    }

    // Epilogue: direct coalesced dword stores (bf16 pair at adjacent w).
    const int wg = nt * 32 + 2 * (lane & 15);
#pragma unroll
    for (int i = 0; i < 2; ++i) {
        int kg = mt * 128 + (wv * 2 + i) * 16 + ((lane >> 4) << 2);
#pragma unroll
        for (int c = 0; c < 3; ++c)
#pragma unroll
            for (int r = 0; r < 4; ++r) {
                uint32_t pk = f2bf(acc[i][2 * c][r]) | (f2bf(acc[i][2 * c + 1][r]) << 16);
                *(uint32_t*)&Y[(size_t)b * 786432 + (size_t)(kg + r) * 1536 + c * 512 + wg] = pk;
            }
    }
}

// ---------------- Pass 2: out[b,k,l,c] = sum_w D[l,w] * Y[b,k,c,w] ----------
// GEMM per b: C[m=kc(96-tile), n=l(128-tile)], K=w, BK=32.
// Both operands staged with global_load_lds (k-dim contiguous in both).
__global__ __launch_bounds__(256, 3) void pass2(const uint16_t* __restrict__ Y,
                                                const uint16_t* __restrict__ Dbf,
                                                float* __restrict__ out) {
    __shared__ __align__(16) char smem[96 * 130 * 4];      // 49920 B
    uint16_t* Alds = (uint16_t*)smem;                      // 96*32 bf16 (6 KB)
    uint16_t* Blds = (uint16_t*)(smem + 6144);             // 128*32 bf16 (8 KB)
    float*    Elds = (float*)smem;                         // 96 x 130 fp32 epilogue
    const int t = threadIdx.x;
    const int lane = t & 63, wv = t >> 6;
    const int lt = blockIdx.x;   // l-tile 0..3
    const int mt = blockIdx.y;   // kc-tile 0..15
    const int b  = blockIdx.z;
    const size_t yb = (size_t)b * 786432;

    f32x4 acc[6][2] = {};

    for (int kt = 0; kt < 16; ++kt) {
        __syncthreads();
        {   // A: Y tile, 96 rows x 64B = 384 chunks
            int q = t;
            load_lds16(Y + yb + (size_t)(mt * 96 + (q >> 2)) * 512 + kt * 32 + (q & 3) * 8,
                       Alds + q * 8);
            if (t < 128) {
                int q2 = 256 + t;
                load_lds16(Y + yb + (size_t)(mt * 96 + (q2 >> 2)) * 512 + kt * 32 + (q2 & 3) * 8,
                           Alds + q2 * 8);
            }
            // B: D tile, 128 rows x 64B = 512 chunks
            int q3 = t;
            load_lds16(Dbf + (size_t)(lt * 128 + (q3 >> 2)) * 512 + kt * 32 + (q3 & 3) * 8,
                       Blds + q3 * 8);
            int q4 = t + 256;
            load_lds16(Dbf + (size_t)(lt * 128 + (q4 >> 2)) * 512 + kt * 32 + (q4 & 3) * 8,
                       Blds + q4 * 8);
        }
        __syncthreads();

        bf16x8 bq[2];
#pragma unroll
        for (int p = 0; p < 2; ++p)
            bq[p] = *(bf16x8*)&Blds[((wv * 2 + p) * 16 + (lane & 15)) * 32 + ((lane >> 4) << 3)];
#pragma unroll
        for (int tt = 0; tt < 6; ++tt) {
            bf16x8 aq = *(bf16x8*)&Alds[(tt * 16 + (lane & 15)) * 32 + ((lane >> 4) << 3)];
            acc[tt][0] = mfma16(aq, bq[0], acc[tt][0]);
            acc[tt][1] = mfma16(aq, bq[1], acc[tt][1]);
        }
    }

    // Epilogue: transpose [kc][l] -> out rows [k][(l,c)] via padded LDS.
    __syncthreads();
#pragma unroll
    for (int tt = 0; tt < 6; ++tt)
#pragma unroll
        for (int p = 0; p < 2; ++p) {
            int m = tt * 16 + ((lane >> 4) << 2);
            int ll = (wv * 2 + p) * 16 + (lane & 15);
#pragma unroll
            for (int r = 0; r < 4; ++r)
                Elds[(m + r) * 130 + ll] = acc[tt][p][r];
        }
    __syncthreads();

    const int kloc = t >> 3, sub = t & 7;   // 32 k-rows, 8 threads per row
    size_t ob = (size_t)b * 786432 + (size_t)(mt * 32 + kloc) * 1536 + lt * 384 + sub * 48;
#pragma unroll
    for (int q = 0; q < 12; ++q) {
        int o0 = sub * 48 + q * 4;
        float4 v;
        v.x = Elds[(kloc * 3 + ((o0 + 0) % 3)) * 130 + (o0 + 0) / 3];
        v.y = Elds[(kloc * 3 + ((o0 + 1) % 3)) * 130 + (o0 + 1) / 3];
        v.z = Elds[(kloc * 3 + ((o0 + 2) % 3)) * 130 + (o0 + 2) / 3];
        v.w = Elds[(kloc * 3 + ((o0 + 3) % 3)) * 130 + (o0 + 3) / 3];
        *(float4*)&out[ob + q * 4] = v;
    }
}

// ---------------------------------------------------------------------------
extern "C" void kernel_launch(void* const* d_in, const int* in_sizes, int n_in,
                              void* d_out, int out_size, void* d_ws, size_t ws_size,
                              hipStream_t stream) {
    (void)in_sizes; (void)n_in; (void)out_size; (void)ws_size;
    const float* x = (const float*)d_in[0];
    float* out = (float*)d_out;
    uint16_t* Dbf = (uint16_t*)d_ws;                 // 512*512 bf16 = 512 KB
    uint16_t* Y   = (uint16_t*)d_ws + 512 * 512;     // 32*512*512*3 bf16 = 48 MB

    gen_dct<<<1024, 256, 0, stream>>>(Dbf);
    dim3 g1(16, 4, 32);
    pass1<<<g1, 256, 0, stream>>>(x, Dbf, Y);
    dim3 g2(4, 16, 32);
    pass2<<<g2, 256, 0, stream>>>(Y, Dbf, out);
}